// Round 4
// baseline (530.261 us; speedup 1.0000x reference)
//
#include <hip/hip_runtime.h>
#include <hip/hip_bf16.h>

#define DD 32   // node/output dim
#define HH 64   // psi hidden
// PSI_IN = 5*32 = 160

typedef __attribute__((ext_vector_type(8))) short bf16x8;   // 8 bf16 = 4 VGPRs
typedef __attribute__((ext_vector_type(4))) float f32x4;
typedef __attribute__((ext_vector_type(4))) unsigned int u32x4;

static __device__ __forceinline__ unsigned short f2bf(float x) {
    union { float f; unsigned u; } v; v.f = x;
    return (unsigned short)((v.u + 0x7FFFu + ((v.u >> 16) & 1u)) >> 16);
}
static __device__ __forceinline__ float bf2f(unsigned short h) {
    union { unsigned u; float f; } v; v.u = ((unsigned)h) << 16; return v.f;
}
// packed f32x2 -> bf16x2 (v_cvt_pk_bf16_f32), low = a
static __device__ __forceinline__ unsigned pk2(float a, float b) {
    __hip_bfloat162 h = __float22bfloat162_rn(make_float2(a, b));
    union { __hip_bfloat162 h2; unsigned u; } cv; cv.h2 = h; return cv.u;
}

// 34 A-operand weight fragments (transposed MLP: M = out-features).
// 16x16x32 A-frag: lane l (c=l&15, q=l>>4): m = t*16+c, k-slot = q*8+j.
//  f 0..19  wf0 (t=f/5, kk=f%5):  k = kk*32 + q*8 + j            <- w0[k][m]
//  f 20..27 wf1 (t,kp):           k = kp*32 + (j>>2)*16 + q*4 + (j&3) <- w1[k][m]
//  f 28..31 wf2 (t,kp):           same interleave                <- w2[k][m]
//  f 32..33 wfW (t):              k = (j>>2)*16 + q*4 + (j&3)    <- W[k][m]
// (interleave = dual-16K trick so layer-i C-layout IS layer-(i+1)'s B-frag)
__global__ __launch_bounds__(256) void prep_weights(
    const float* __restrict__ w0, const float* __restrict__ w1,
    const float* __restrict__ w2, const float* __restrict__ W,
    unsigned short* __restrict__ frags)
{
    const int tid = blockIdx.x * 256 + threadIdx.x;
    const int f = tid >> 6, l = tid & 63;
    if (f >= 34) return;
    const int c = l & 15, q = l >> 4;
    unsigned short* dst = frags + f * 512 + l * 8;
    if (f < 20) {
        const int t = f / 5, kk = f % 5, m = t * 16 + c;
        #pragma unroll
        for (int j = 0; j < 8; ++j)
            dst[j] = f2bf(w0[(kk * 32 + q * 8 + j) * HH + m]);
    } else if (f < 28) {
        const int f1 = f - 20, t = f1 >> 1, kp = f1 & 1, m = t * 16 + c;
        #pragma unroll
        for (int j = 0; j < 8; ++j)
            dst[j] = f2bf(w1[(kp * 32 + (j >> 2) * 16 + q * 4 + (j & 3)) * HH + m]);
    } else if (f < 32) {
        const int f2i = f - 28, t = f2i >> 1, kp = f2i & 1, m = t * 16 + c;
        #pragma unroll
        for (int j = 0; j < 8; ++j)
            dst[j] = f2bf(w2[(kp * 32 + (j >> 2) * 16 + q * 4 + (j & 3)) * DD + m]);
    } else {
        const int t = f - 32, m = t * 16 + c;
        #pragma unroll
        for (int j = 0; j < 8; ++j)
            dst[j] = f2bf(W[((j >> 2) * 16 + q * 4 + (j & 3)) * DD + m]);
    }
}

// One wave per 16-edge tile. Transposed zero-interlayer-LDS MLP + fused W,
// atomics straight into out (pre-filled with h_d_prev).
// Weights wf0/wf1/wf2 staged in LDS (32 KB/block, conflict-free b128 reads);
// wfW (8 VGPRs) in registers. Epilogue transposes the 16x32 tile through a
// per-wave bf16 LDS scratch so atomics are 4 rows x 16 contiguous dwords.
__global__ __launch_bounds__(256, 4) void edge_mfma(
    const float* __restrict__ h_d, const float* __restrict__ h_s,
    const float* __restrict__ ef,
    const int* __restrict__ snd, const int* __restrict__ rcv,
    const unsigned short* __restrict__ frags,
    const float* __restrict__ b0, const float* __restrict__ b1,
    const float* __restrict__ b2,
    float* __restrict__ out, int E, int ntiles)
{
    __shared__ __align__(16) unsigned short wlds[32 * 512];   // 32 KB weight frags
    __shared__ __align__(16) unsigned short sbuf[4][16 * 40]; // 5 KB bf16 transpose scratch

    const int tid = threadIdx.x;
    const int lane = tid & 63, w = tid >> 6;
    const int c = lane & 15, q = lane >> 4;

    // stage wf0+wf1+wf2 -> LDS (2048 u32x4)
    {
        const u32x4* src = (const u32x4*)frags;
        u32x4* dst = (u32x4*)wlds;
        #pragma unroll
        for (int i = 0; i < 8; ++i) dst[tid + i * 256] = src[tid + i * 256];
    }
    // wfW -> registers
    bf16x8 wfW0 = *(const bf16x8*)(frags + 32 * 512 + lane * 8);
    bf16x8 wfW1 = *(const bf16x8*)(frags + 33 * 512 + lane * 8);
    __syncthreads();

    // bias fragments: feature = t*16 + q*4 + r
    f32x4 b0v[4], b1v[4], b2v[2];
    #pragma unroll
    for (int t = 0; t < 4; ++t) b0v[t] = *(const f32x4*)(b0 + t * 16 + q * 4);
    #pragma unroll
    for (int t = 0; t < 4; ++t) b1v[t] = *(const f32x4*)(b1 + t * 16 + q * 4);
    #pragma unroll
    for (int t = 0; t < 2; ++t) b2v[t] = *(const f32x4*)(b2 + t * 16 + q * 4);

    unsigned short* sw = sbuf[w];
    const int nw = gridDim.x * 4;
    int tile = blockIdx.x * 4 + w;
    if (tile >= ntiles) return;

    // current tile's indices (prefetched pattern: si/ri always ready at loop top)
    int e0 = tile * 16 + c; if (e0 >= E) e0 = E - 1;
    int si = snd[e0], ri = rcv[e0];

    while (true) {
        const int base = tile * 16;
        int ec = base + c; if (ec >= E) ec = E - 1;

        const float* s0 = h_s + (size_t)si * DD;
        const float* s1 = h_s + (size_t)ri * DD;
        const float* s2 = h_d + (size_t)si * DD;   // h_di
        const float* s3 = h_d + (size_t)ri * DD;   // h_dj
        const float* s4 = ef  + (size_t)ec * DD;

        // gathers for this tile (issued up front)
        f32x4 g[10];
        const float* srcs[5] = {s0, s1, s2, s3, s4};
        #pragma unroll
        for (int kk = 0; kk < 5; ++kk) {
            g[2 * kk]     = *(const f32x4*)(srcs[kk] + q * 8);
            g[2 * kk + 1] = *(const f32x4*)(srcs[kk] + q * 8 + 4);
        }
        f32x4 di[2], dj[2];
        #pragma unroll
        for (int t = 0; t < 2; ++t) {
            di[t] = *(const f32x4*)(s2 + t * 16 + q * 4);
            dj[t] = *(const f32x4*)(s3 + t * 16 + q * 4);
        }

        // prefetch next tile's indices
        const int ntile = tile + nw;
        int nsi = si, nri = ri;
        if (ntile < ntiles) {
            int en = ntile * 16 + c; if (en >= E) en = E - 1;
            nsi = snd[en]; nri = rcv[en];
        }

        // ---- layer 0: X1^T = W0^T @ X0^T, B straight from gathers ----
        f32x4 c0[4] = {b0v[0], b0v[1], b0v[2], b0v[3]};
        #pragma unroll
        for (int kk = 0; kk < 5; ++kk) {
            union { unsigned u[4]; bf16x8 v; } bb;
            bb.u[0] = pk2(g[2 * kk][0], g[2 * kk][1]);
            bb.u[1] = pk2(g[2 * kk][2], g[2 * kk][3]);
            bb.u[2] = pk2(g[2 * kk + 1][0], g[2 * kk + 1][1]);
            bb.u[3] = pk2(g[2 * kk + 1][2], g[2 * kk + 1][3]);
            #pragma unroll
            for (int t = 0; t < 4; ++t) {
                const bf16x8 a = *(const bf16x8*)(wlds + (t * 5 + kk) * 512 + lane * 8);
                c0[t] = __builtin_amdgcn_mfma_f32_16x16x32_bf16(a, bb.v, c0[t], 0, 0, 0);
            }
        }
        unsigned x1[4][2];
        #pragma unroll
        for (int kt = 0; kt < 4; ++kt) {
            x1[kt][0] = pk2(fmaxf(c0[kt][0], 0.f), fmaxf(c0[kt][1], 0.f));
            x1[kt][1] = pk2(fmaxf(c0[kt][2], 0.f), fmaxf(c0[kt][3], 0.f));
        }

        // ---- layer 1 ----
        f32x4 c1[4] = {b1v[0], b1v[1], b1v[2], b1v[3]};
        #pragma unroll
        for (int kp = 0; kp < 2; ++kp) {
            union { unsigned u[4]; bf16x8 v; } bb;
            bb.u[0] = x1[2 * kp][0];     bb.u[1] = x1[2 * kp][1];
            bb.u[2] = x1[2 * kp + 1][0]; bb.u[3] = x1[2 * kp + 1][1];
            #pragma unroll
            for (int t = 0; t < 4; ++t) {
                const bf16x8 a = *(const bf16x8*)(wlds + (20 + t * 2 + kp) * 512 + lane * 8);
                c1[t] = __builtin_amdgcn_mfma_f32_16x16x32_bf16(a, bb.v, c1[t], 0, 0, 0);
            }
        }
        unsigned x2[4][2];
        #pragma unroll
        for (int kt = 0; kt < 4; ++kt) {
            x2[kt][0] = pk2(fmaxf(c1[kt][0], 0.f), fmaxf(c1[kt][1], 0.f));
            x2[kt][1] = pk2(fmaxf(c1[kt][2], 0.f), fmaxf(c1[kt][3], 0.f));
        }

        // ---- layer 2 ----
        f32x4 c2[2] = {b2v[0], b2v[1]};
        #pragma unroll
        for (int kp = 0; kp < 2; ++kp) {
            union { unsigned u[4]; bf16x8 v; } bb;
            bb.u[0] = x2[2 * kp][0];     bb.u[1] = x2[2 * kp][1];
            bb.u[2] = x2[2 * kp + 1][0]; bb.u[3] = x2[2 * kp + 1][1];
            #pragma unroll
            for (int t = 0; t < 2; ++t) {
                const bf16x8 a = *(const bf16x8*)(wlds + (28 + t * 2 + kp) * 512 + lane * 8);
                c2[t] = __builtin_amdgcn_mfma_f32_16x16x32_bf16(a, bb.v, c2[t], 0, 0, 0);
            }
        }

        // ---- s_ij = relu(psi) * (h_dj - h_di), then fused @W (2 MFMAs) ----
        union { unsigned u[4]; bf16x8 v; } sb;
        {
            float s00 = fmaxf(c2[0][0], 0.f) * (dj[0][0] - di[0][0]);
            float s01 = fmaxf(c2[0][1], 0.f) * (dj[0][1] - di[0][1]);
            float s02 = fmaxf(c2[0][2], 0.f) * (dj[0][2] - di[0][2]);
            float s03 = fmaxf(c2[0][3], 0.f) * (dj[0][3] - di[0][3]);
            float s10 = fmaxf(c2[1][0], 0.f) * (dj[1][0] - di[1][0]);
            float s11 = fmaxf(c2[1][1], 0.f) * (dj[1][1] - di[1][1]);
            float s12 = fmaxf(c2[1][2], 0.f) * (dj[1][2] - di[1][2]);
            float s13 = fmaxf(c2[1][3], 0.f) * (dj[1][3] - di[1][3]);
            sb.u[0] = pk2(s00, s01); sb.u[1] = pk2(s02, s03);
            sb.u[2] = pk2(s10, s11); sb.u[3] = pk2(s12, s13);
        }
        f32x4 zero = {0.f, 0.f, 0.f, 0.f};
        f32x4 c3[2];
        c3[0] = __builtin_amdgcn_mfma_f32_16x16x32_bf16(wfW0, sb.v, zero, 0, 0, 0);
        c3[1] = __builtin_amdgcn_mfma_f32_16x16x32_bf16(wfW1, sb.v, zero, 0, 0, 0);

        // ---- transpose via per-wave bf16 scratch, then coalesced atomics ----
        // write: lane(c,q) owns edge c, feats 16t+4q..+3  (stride 40 shorts)
        #pragma unroll
        for (int t = 0; t < 2; ++t) {
            uint2 pv;
            pv.x = pk2(c3[t][0], c3[t][1]);
            pv.y = pk2(c3[t][2], c3[t][3]);
            *(uint2*)(sw + c * 40 + t * 16 + q * 4) = pv;
        }
        // read R2-pattern: instr (t,r): lane(c,q) -> edge 4q+r, feat 16t+c
        #pragma unroll
        for (int r = 0; r < 4; ++r) {
            const int er = base + q * 4 + r;
            if (er < E) {
                const int rr = rcv[er];
                const float v0 = bf2f(sw[(q * 4 + r) * 40 + c]);
                const float v1 = bf2f(sw[(q * 4 + r) * 40 + 16 + c]);
                atomicAdd(out + (size_t)rr * DD + c, v0);
                atomicAdd(out + (size_t)rr * DD + 16 + c, v1);
            }
        }

        if (ntile >= ntiles) break;
        tile = ntile; si = nsi; ri = nri;
    }
}

extern "C" void kernel_launch(void* const* d_in, const int* in_sizes, int n_in,
                              void* d_out, int out_size, void* d_ws, size_t ws_size,
                              hipStream_t stream) {
    const float* h_d = (const float*)d_in[0];
    const float* h_s = (const float*)d_in[1];
    const float* ef  = (const float*)d_in[2];
    const int*   snd = (const int*)d_in[3];
    const int*   rcv = (const int*)d_in[4];
    const float* w0  = (const float*)d_in[5];
    const float* b0  = (const float*)d_in[6];
    const float* w1  = (const float*)d_in[7];
    const float* b1  = (const float*)d_in[8];
    const float* w2  = (const float*)d_in[9];
    const float* b2  = (const float*)d_in[10];
    const float* W   = (const float*)d_in[11];
    float* out = (float*)d_out;

    const int N = in_sizes[0] / DD;
    const int E = in_sizes[3];
    const int ntiles = (E + 15) / 16;

    unsigned short* frags = (unsigned short*)d_ws;   // 34 KB

    // out = h_d_prev, then edge kernel atomically adds scatter(s_ij @ W)
    hipMemcpyAsync(out, h_d, (size_t)N * DD * sizeof(float),
                   hipMemcpyDeviceToDevice, stream);
    prep_weights<<<9, 256, 0, stream>>>(w0, w1, w2, W, frags);
    edge_mfma<<<1024, 256, 0, stream>>>(h_d, h_s, ef, snd, rcv, frags,
                                        b0, b1, b2, out, E, ntiles);
}